// Round 2
// baseline (975.311 us; speedup 1.0000x reference)
//
#include <hip/hip_runtime.h>

#define IN_DIM  3
#define HID_DIM 20
#define OUT_DIM 3
#define N_EXP   5
#define ELEMS   4
#define BLOCK   256

// d_out layout: mixed [B,3] followed by gate [B,5], both fp32.
// Thread t of a block handles elements blockBase + t + c*BLOCK (c=0..ELEMS-1):
// every global load/store instruction is a contiguous lane-coalesced span
// (12B or 20B lane stride), eliminating the round-1 partial-line write
// amplification (WRITE_SIZE 209MB -> ~33MB predicted).

__global__ __launch_bounds__(BLOCK, 4) void moe_kernel(
    const float* __restrict__ x,
    const float* __restrict__ W1,   // [E, IN, HID]
    const float* __restrict__ b1,   // [E, HID]
    const float* __restrict__ W2,   // [E, HID, OUT]
    const float* __restrict__ b2,   // [E, OUT]
    const float* __restrict__ Wg,   // [IN, E]
    const float* __restrict__ bg,   // [E]
    float* __restrict__ out,
    int B)
{
    __shared__ float sW1[N_EXP * IN_DIM * HID_DIM];   // 300
    __shared__ float sB1[N_EXP * HID_DIM];            // 100
    __shared__ float sW2[N_EXP * HID_DIM * OUT_DIM];  // 300
    __shared__ float sB2[N_EXP * OUT_DIM];            // 15
    __shared__ float sWg[IN_DIM * N_EXP];             // 15
    __shared__ float sBg[N_EXP];                      // 5

    {
        const int t = threadIdx.x;
        for (int i = t; i < N_EXP * IN_DIM * HID_DIM; i += BLOCK) sW1[i] = W1[i];
        for (int i = t; i < N_EXP * HID_DIM; i += BLOCK)          sB1[i] = b1[i];
        for (int i = t; i < N_EXP * HID_DIM * OUT_DIM; i += BLOCK) sW2[i] = W2[i];
        if (t < N_EXP * OUT_DIM) sB2[t] = b2[t];
        if (t < IN_DIM * N_EXP)  sWg[t] = Wg[t];
        if (t < N_EXP)           sBg[t] = bg[t];
    }
    __syncthreads();

    const long long blockBase = (long long)blockIdx.x * (BLOCK * ELEMS);
    const int t = threadIdx.x;

    float* __restrict__ mixed_out = out;
    float* __restrict__ gate_out  = out + (long long)B * OUT_DIM;

    // element indices handled by this thread (strided for coalescing)
    long long idx[ELEMS];
    bool      ok[ELEMS];
    #pragma unroll
    for (int c = 0; c < ELEMS; ++c) {
        idx[c] = blockBase + c * BLOCK + t;
        ok[c]  = idx[c] < (long long)B;
    }

    // ---------- coalesced x loads (lane stride 12B per instruction) ----------
    float xf[ELEMS * IN_DIM];
    #pragma unroll
    for (int c = 0; c < ELEMS; ++c) {
        #pragma unroll
        for (int i = 0; i < IN_DIM; ++i)
            xf[c * IN_DIM + i] = ok[c] ? x[idx[c] * IN_DIM + i] : 0.f;
    }

    // ---------- gate: softmax(x @ Wg + bg), no max-sub (|logit| small) -------
    float gate[ELEMS][N_EXP];
    #pragma unroll
    for (int c = 0; c < ELEMS; ++c) {
        float lg[N_EXP];
        float s = 0.f;
        #pragma unroll
        for (int e = 0; e < N_EXP; ++e) {
            float v = sBg[e];
            #pragma unroll
            for (int i = 0; i < IN_DIM; ++i)
                v = fmaf(xf[c * IN_DIM + i], sWg[i * N_EXP + e], v);
            v = __expf(v);
            lg[e] = v;
            s += v;
        }
        const float inv = 1.0f / s;
        #pragma unroll
        for (int e = 0; e < N_EXP; ++e) gate[c][e] = lg[e] * inv;
    }

    // ---------- experts: streamed over hidden units, LDS reads amortized ----
    float mix[ELEMS][OUT_DIM];
    #pragma unroll
    for (int c = 0; c < ELEMS; ++c)
        #pragma unroll
        for (int k = 0; k < OUT_DIM; ++k) mix[c][k] = 0.f;

    #pragma unroll
    for (int e = 0; e < N_EXP; ++e) {
        float oacc[ELEMS][OUT_DIM];
        #pragma unroll
        for (int c = 0; c < ELEMS; ++c)
            #pragma unroll
            for (int k = 0; k < OUT_DIM; ++k)
                oacc[c][k] = sB2[e * OUT_DIM + k];

        #pragma unroll
        for (int j = 0; j < HID_DIM; ++j) {
            // 7 wave-uniform LDS reads reused across ELEMS elements (28 FMAs)
            const float w10 = sW1[(e * IN_DIM + 0) * HID_DIM + j];
            const float w11 = sW1[(e * IN_DIM + 1) * HID_DIM + j];
            const float w12 = sW1[(e * IN_DIM + 2) * HID_DIM + j];
            const float bb  = sB1[e * HID_DIM + j];
            const float w20 = sW2[(e * HID_DIM + j) * OUT_DIM + 0];
            const float w21 = sW2[(e * HID_DIM + j) * OUT_DIM + 1];
            const float w22 = sW2[(e * HID_DIM + j) * OUT_DIM + 2];
            #pragma unroll
            for (int c = 0; c < ELEMS; ++c) {
                float h = fmaf(xf[c * IN_DIM + 2], w12,
                          fmaf(xf[c * IN_DIM + 1], w11,
                          fmaf(xf[c * IN_DIM + 0], w10, bb)));
                h = fmaxf(h, 0.f);
                oacc[c][0] = fmaf(h, w20, oacc[c][0]);
                oacc[c][1] = fmaf(h, w21, oacc[c][1]);
                oacc[c][2] = fmaf(h, w22, oacc[c][2]);
            }
        }

        #pragma unroll
        for (int c = 0; c < ELEMS; ++c)
            #pragma unroll
            for (int k = 0; k < OUT_DIM; ++k)
                mix[c][k] = fmaf(gate[c][e], oacc[c][k], mix[c][k]);
    }

    // ---------- coalesced stores (lane stride 12B / 20B per instruction) ----
    #pragma unroll
    for (int c = 0; c < ELEMS; ++c) {
        if (ok[c]) {
            #pragma unroll
            for (int k = 0; k < OUT_DIM; ++k)
                mixed_out[idx[c] * OUT_DIM + k] = mix[c][k];
            #pragma unroll
            for (int e = 0; e < N_EXP; ++e)
                gate_out[idx[c] * N_EXP + e] = gate[c][e];
        }
    }
}

extern "C" void kernel_launch(void* const* d_in, const int* in_sizes, int n_in,
                              void* d_out, int out_size, void* d_ws, size_t ws_size,
                              hipStream_t stream) {
    const float* x  = (const float*)d_in[0];
    const float* W1 = (const float*)d_in[1];
    const float* b1 = (const float*)d_in[2];
    const float* W2 = (const float*)d_in[3];
    const float* b2 = (const float*)d_in[4];
    const float* Wg = (const float*)d_in[5];
    const float* bg = (const float*)d_in[6];
    float* out = (float*)d_out;

    const int B = in_sizes[0] / IN_DIM;
    const int per_block = BLOCK * ELEMS;
    const int grid = (B + per_block - 1) / per_block;

    moe_kernel<<<grid, BLOCK, 0, stream>>>(x, W1, b1, W2, b2, Wg, bg, out, B);
}

// Round 3
// 180.781 us; speedup vs baseline: 5.3950x; 5.3950x over previous
//
#include <hip/hip_runtime.h>

#define IN_DIM  3
#define HID_DIM 20
#define OUT_DIM 3
#define N_EXP   5
#define ELEMS   4
#define BLOCK   256
#define SPAN    (BLOCK * ELEMS)   // 1024 elements per block

// d_out layout: mixed [B,3] then gate [B,5], fp32.
// All global I/O is staged through LDS so every global instruction is a
// dense contiguous float4 per lane (1 KiB/wave-instr). R1/R2 showed strided
// lane scatters amplify WRITE_SIZE 6-26x and forced-VGPR spills cost 2.5 GB.

__global__ __launch_bounds__(BLOCK, 2) void moe_kernel(
    const float* __restrict__ x,
    const float* __restrict__ W1,   // [E, IN, HID]
    const float* __restrict__ b1,   // [E, HID]
    const float* __restrict__ W2,   // [E, HID, OUT]
    const float* __restrict__ b2,   // [E, OUT]
    const float* __restrict__ Wg,   // [IN, E]
    const float* __restrict__ bg,   // [E]
    float* __restrict__ out,
    int B)
{
    __shared__ float4 sWp[N_EXP * HID_DIM * 2];  // (w10,w11,w12,b1),(w20,w21,w22,0) per (e,j)
    __shared__ float4 sB2p[N_EXP];
    __shared__ float  sWg[IN_DIM * N_EXP];
    __shared__ float  sBg[N_EXP];
    __shared__ float  sBuf[SPAN * IN_DIM];       // x staging, reused for mixed (12 KB)
    __shared__ float  sGate[SPAN * N_EXP];       // 20 KB

    const int t = threadIdx.x;

    // ---- preamble: pack weights into LDS (one-time, tiny) ----
    if (t < N_EXP * HID_DIM) {                   // 100 threads
        const int e = t / HID_DIM, j = t % HID_DIM;
        float4 a, b;
        a.x = W1[(e * IN_DIM + 0) * HID_DIM + j];
        a.y = W1[(e * IN_DIM + 1) * HID_DIM + j];
        a.z = W1[(e * IN_DIM + 2) * HID_DIM + j];
        a.w = b1[e * HID_DIM + j];
        b.x = W2[(e * HID_DIM + j) * OUT_DIM + 0];
        b.y = W2[(e * HID_DIM + j) * OUT_DIM + 1];
        b.z = W2[(e * HID_DIM + j) * OUT_DIM + 2];
        b.w = 0.f;
        sWp[2 * t]     = a;
        sWp[2 * t + 1] = b;
    } else if (t >= 128 && t < 128 + N_EXP) {
        const int e = t - 128;
        sB2p[e] = make_float4(b2[e * OUT_DIM + 0], b2[e * OUT_DIM + 1],
                              b2[e * OUT_DIM + 2], 0.f);
    } else if (t >= 160 && t < 160 + IN_DIM * N_EXP) {
        sWg[t - 160] = Wg[t - 160];
    } else if (t >= 192 && t < 192 + N_EXP) {
        sBg[t - 192] = bg[t - 192];
    }

    const long long blockBase = (long long)blockIdx.x * SPAN;
    float* __restrict__ mixed_out = out;
    float* __restrict__ gate_out  = out + (long long)B * OUT_DIM;

    const bool fast = (blockBase + SPAN <= (long long)B) && ((B & 3) == 0);

    if (fast) {
        const int bb = (int)blockBase;           // fits: B ≤ 2^31/8

        // ---- cooperative dense x load: 3072 floats = 768 float4 ----
        {
            const float4* g4 = reinterpret_cast<const float4*>(x + (size_t)bb * IN_DIM);
            float4* s4 = reinterpret_cast<float4*>(sBuf);
            #pragma unroll
            for (int k = 0; k < (SPAN * IN_DIM) / (4 * BLOCK); ++k)   // 3
                s4[t + k * BLOCK] = g4[t + k * BLOCK];
        }
        __syncthreads();   // covers weight preamble + x staging

        // ---- per-thread x: elements 4t..4t+3 → float4 slots 3t..3t+2 ----
        float xf[ELEMS * IN_DIM];
        {
            const float4* s4 = reinterpret_cast<const float4*>(sBuf);
            #pragma unroll
            for (int k = 0; k < 3; ++k) {
                float4 v = s4[3 * t + k];
                xf[4 * k + 0] = v.x; xf[4 * k + 1] = v.y;
                xf[4 * k + 2] = v.z; xf[4 * k + 3] = v.w;
            }
        }

        // ---- gate: softmax(x @ Wg + bg); scatter to LDS gate area ----
        float gate[ELEMS][N_EXP];
        #pragma unroll
        for (int c = 0; c < ELEMS; ++c) {
            float lg[N_EXP];
            float s = 0.f;
            #pragma unroll
            for (int e = 0; e < N_EXP; ++e) {
                float v = sBg[e];
                #pragma unroll
                for (int i = 0; i < IN_DIM; ++i)
                    v = fmaf(xf[c * IN_DIM + i], sWg[i * N_EXP + e], v);
                v = __expf(v);
                lg[e] = v; s += v;
            }
            const float inv = 1.0f / s;
            #pragma unroll
            for (int e = 0; e < N_EXP; ++e) {
                gate[c][e] = lg[e] * inv;
                sGate[(ELEMS * t + c) * N_EXP + e] = gate[c][e];
            }
        }

        // ---- experts: streamed j-loop, packed b128 broadcast weight reads --
        float mix[ELEMS][OUT_DIM];
        #pragma unroll
        for (int c = 0; c < ELEMS; ++c)
            #pragma unroll
            for (int k = 0; k < OUT_DIM; ++k) mix[c][k] = 0.f;

        #pragma unroll
        for (int e = 0; e < N_EXP; ++e) {
            const float4 bb2 = sB2p[e];
            float oacc[ELEMS][OUT_DIM];
            #pragma unroll
            for (int c = 0; c < ELEMS; ++c) {
                oacc[c][0] = bb2.x; oacc[c][1] = bb2.y; oacc[c][2] = bb2.z;
            }
            #pragma unroll
            for (int j = 0; j < HID_DIM; ++j) {
                const float4 a  = sWp[(e * HID_DIM + j) * 2];      // w10,w11,w12,b1
                const float4 w2 = sWp[(e * HID_DIM + j) * 2 + 1];  // w20,w21,w22,-
                #pragma unroll
                for (int c = 0; c < ELEMS; ++c) {
                    float h = fmaf(xf[c * IN_DIM + 2], a.z,
                              fmaf(xf[c * IN_DIM + 1], a.y,
                              fmaf(xf[c * IN_DIM + 0], a.x, a.w)));
                    h = fmaxf(h, 0.f);
                    oacc[c][0] = fmaf(h, w2.x, oacc[c][0]);
                    oacc[c][1] = fmaf(h, w2.y, oacc[c][1]);
                    oacc[c][2] = fmaf(h, w2.z, oacc[c][2]);
                }
            }
            #pragma unroll
            for (int c = 0; c < ELEMS; ++c)
                #pragma unroll
                for (int k = 0; k < OUT_DIM; ++k)
                    mix[c][k] = fmaf(gate[c][e], oacc[c][k], mix[c][k]);
        }

        // ---- write mixed into sBuf (same float4 slots this thread read) ----
        {
            float4* s4 = reinterpret_cast<float4*>(sBuf);
            float m[ELEMS * OUT_DIM];
            #pragma unroll
            for (int c = 0; c < ELEMS; ++c)
                #pragma unroll
                for (int k = 0; k < OUT_DIM; ++k)
                    m[c * OUT_DIM + k] = mix[c][k];
            #pragma unroll
            for (int k = 0; k < 3; ++k)
                s4[3 * t + k] = make_float4(m[4 * k + 0], m[4 * k + 1],
                                            m[4 * k + 2], m[4 * k + 3]);
        }
        __syncthreads();

        // ---- cooperative dense stores: mixed 768 float4, gate 1280 float4 --
        {
            float4* o4 = reinterpret_cast<float4*>(mixed_out + (size_t)bb * OUT_DIM);
            const float4* s4 = reinterpret_cast<const float4*>(sBuf);
            #pragma unroll
            for (int k = 0; k < (SPAN * OUT_DIM) / (4 * BLOCK); ++k)  // 3
                o4[t + k * BLOCK] = s4[t + k * BLOCK];
        }
        {
            float4* o4 = reinterpret_cast<float4*>(gate_out + (size_t)bb * N_EXP);
            const float4* s4 = reinterpret_cast<const float4*>(sGate);
            #pragma unroll
            for (int k = 0; k < (SPAN * N_EXP) / (4 * BLOCK); ++k)    // 5
                o4[t + k * BLOCK] = s4[t + k * BLOCK];
        }
    } else {
        // ---- guarded scalar tail path (not taken at B = 1M) ----
        __syncthreads();   // weight preamble visible
        for (int c = 0; c < ELEMS; ++c) {
            const long long bidx = blockBase + (long long)ELEMS * t + c;
            if (bidx >= (long long)B) continue;
            float xv[IN_DIM];
            for (int i = 0; i < IN_DIM; ++i) xv[i] = x[bidx * IN_DIM + i];

            float lg[N_EXP]; float s = 0.f;
            for (int e = 0; e < N_EXP; ++e) {
                float v = sBg[e];
                for (int i = 0; i < IN_DIM; ++i)
                    v = fmaf(xv[i], sWg[i * N_EXP + e], v);
                v = __expf(v); lg[e] = v; s += v;
            }
            const float inv = 1.0f / s;
            for (int e = 0; e < N_EXP; ++e) lg[e] *= inv;

            float mixv[OUT_DIM] = {0.f, 0.f, 0.f};
            for (int e = 0; e < N_EXP; ++e) {
                const float4 bb2 = sB2p[e];
                float oa[OUT_DIM] = {bb2.x, bb2.y, bb2.z};
                for (int j = 0; j < HID_DIM; ++j) {
                    const float4 a  = sWp[(e * HID_DIM + j) * 2];
                    const float4 w2 = sWp[(e * HID_DIM + j) * 2 + 1];
                    float h = fmaf(xv[2], a.z, fmaf(xv[1], a.y, fmaf(xv[0], a.x, a.w)));
                    h = fmaxf(h, 0.f);
                    oa[0] = fmaf(h, w2.x, oa[0]);
                    oa[1] = fmaf(h, w2.y, oa[1]);
                    oa[2] = fmaf(h, w2.z, oa[2]);
                }
                for (int k = 0; k < OUT_DIM; ++k)
                    mixv[k] = fmaf(lg[e], oa[k], mixv[k]);
            }
            for (int k = 0; k < OUT_DIM; ++k)
                mixed_out[bidx * OUT_DIM + k] = mixv[k];
            for (int e = 0; e < N_EXP; ++e)
                gate_out[bidx * N_EXP + e] = lg[e];
        }
    }
}

extern "C" void kernel_launch(void* const* d_in, const int* in_sizes, int n_in,
                              void* d_out, int out_size, void* d_ws, size_t ws_size,
                              hipStream_t stream) {
    const float* x  = (const float*)d_in[0];
    const float* W1 = (const float*)d_in[1];
    const float* b1 = (const float*)d_in[2];
    const float* W2 = (const float*)d_in[3];
    const float* b2 = (const float*)d_in[4];
    const float* Wg = (const float*)d_in[5];
    const float* bg = (const float*)d_in[6];
    float* out = (float*)d_out;

    const int B = in_sizes[0] / IN_DIM;
    const int grid = (B + SPAN - 1) / SPAN;

    moe_kernel<<<grid, BLOCK, 0, stream>>>(x, W1, b1, W2, b2, Wg, bg, out, B);
}

// Round 4
// 108.951 us; speedup vs baseline: 8.9518x; 1.6593x over previous
//
#include <hip/hip_runtime.h>

#define IN_DIM  3
#define HID_DIM 20
#define OUT_DIM 3
#define N_EXP   5
#define ELEMS   4
#define BLOCK   256
#define SPAN    (BLOCK * ELEMS)   // 1024 elements per block

// d_out layout: mixed [B,3] then gate [B,5], fp32.
// R1-R3 post-mortem: extra HBM traffic tracked VGPR spill pressure (R2 spills
// = 2.4GB scratch traffic; R1/R3 clamped exactly at 256/128 cliffs). This
// round: no VGPR clamp, live state ~55 regs (oacc folded away), weights read
// as wave-uniform scalar loads (no LDS weight pipe), LDS only for dense I/O
// staging. All global I/O is contiguous float4 per lane.

__global__ __launch_bounds__(BLOCK) void moe_kernel(
    const float* __restrict__ x,
    const float* __restrict__ W1,   // [E, IN, HID]
    const float* __restrict__ b1,   // [E, HID]
    const float* __restrict__ W2,   // [E, HID, OUT]
    const float* __restrict__ b2,   // [E, OUT]
    const float* __restrict__ Wg,   // [IN, E]
    const float* __restrict__ bg,   // [E]
    float* __restrict__ out,
    int B)
{
    __shared__ float sIO[SPAN * N_EXP];   // 20 KB, reused: x -> gate -> mixed

    const int t = threadIdx.x;
    const long long blockBase = (long long)blockIdx.x * SPAN;
    float* __restrict__ mixed_out = out;
    float* __restrict__ gate_out  = out + (long long)B * OUT_DIM;

    if (blockBase + SPAN <= (long long)B) {
        const size_t bb = (size_t)blockBase;

        // ---- 1. cooperative dense x load: 768 float4 ----
        {
            const float4* g4 = reinterpret_cast<const float4*>(x + bb * IN_DIM);
            float4* s4 = reinterpret_cast<float4*>(sIO);
            #pragma unroll
            for (int k = 0; k < 3; ++k) s4[t + k * BLOCK] = g4[t + k * BLOCK];
        }
        __syncthreads();

        // ---- 2. per-thread x fragments (elements 4t..4t+3) ----
        float xf[ELEMS * IN_DIM];
        {
            const float4* s4 = reinterpret_cast<const float4*>(sIO);
            #pragma unroll
            for (int k = 0; k < 3; ++k) {
                float4 v = s4[3 * t + k];
                xf[4 * k + 0] = v.x; xf[4 * k + 1] = v.y;
                xf[4 * k + 2] = v.z; xf[4 * k + 3] = v.w;
            }
        }
        __syncthreads();   // all x reads done before sIO is overwritten

        // ---- 3. gate: softmax(x @ Wg + bg); weights are uniform scalar loads
        float gate[ELEMS][N_EXP];
        #pragma unroll
        for (int c = 0; c < ELEMS; ++c) {
            float lg[N_EXP]; float s = 0.f;
            #pragma unroll
            for (int e = 0; e < N_EXP; ++e) {
                float v = bg[e];
                #pragma unroll
                for (int i = 0; i < IN_DIM; ++i)
                    v = fmaf(xf[c * IN_DIM + i], Wg[i * N_EXP + e], v);
                v = __expf(v);
                lg[e] = v; s += v;
            }
            const float inv = 1.0f / s;
            #pragma unroll
            for (int e = 0; e < N_EXP; ++e) gate[c][e] = lg[e] * inv;
        }
        // gate -> LDS as 5 aligned float4 per thread
        {
            float4* s4 = reinterpret_cast<float4*>(sIO);
            float g[ELEMS * N_EXP];
            #pragma unroll
            for (int c = 0; c < ELEMS; ++c)
                #pragma unroll
                for (int e = 0; e < N_EXP; ++e) g[c * N_EXP + e] = gate[c][e];
            #pragma unroll
            for (int k = 0; k < 5; ++k)
                s4[5 * t + k] = make_float4(g[4 * k + 0], g[4 * k + 1],
                                            g[4 * k + 2], g[4 * k + 3]);
        }
        __syncthreads();

        // ---- 4. cooperative dense gate store: 1280 float4 ----
        {
            float4* o4 = reinterpret_cast<float4*>(gate_out + bb * N_EXP);
            const float4* s4 = reinterpret_cast<const float4*>(sIO);
            #pragma unroll
            for (int k = 0; k < 5; ++k) o4[t + k * BLOCK] = s4[t + k * BLOCK];
        }

        // ---- 5. experts: b2 folded through gate; no oacc buffer ----
        float mix[ELEMS][OUT_DIM];
        #pragma unroll
        for (int c = 0; c < ELEMS; ++c) {
            #pragma unroll
            for (int k = 0; k < OUT_DIM; ++k) {
                float m = 0.f;
                #pragma unroll
                for (int e = 0; e < N_EXP; ++e)
                    m = fmaf(gate[c][e], b2[e * OUT_DIM + k], m);
                mix[c][k] = m;
            }
        }
        #pragma unroll
        for (int e = 0; e < N_EXP; ++e) {
            #pragma unroll
            for (int j = 0; j < HID_DIM; ++j) {
                // 7 wave-uniform weight loads (scalar-cache) per (e,j)
                const float w10 = W1[(e * IN_DIM + 0) * HID_DIM + j];
                const float w11 = W1[(e * IN_DIM + 1) * HID_DIM + j];
                const float w12 = W1[(e * IN_DIM + 2) * HID_DIM + j];
                const float bb1 = b1[e * HID_DIM + j];
                const float w20 = W2[(e * HID_DIM + j) * OUT_DIM + 0];
                const float w21 = W2[(e * HID_DIM + j) * OUT_DIM + 1];
                const float w22 = W2[(e * HID_DIM + j) * OUT_DIM + 2];
                #pragma unroll
                for (int c = 0; c < ELEMS; ++c) {
                    float h = fmaf(xf[c * IN_DIM + 2], w12,
                              fmaf(xf[c * IN_DIM + 1], w11,
                              fmaf(xf[c * IN_DIM + 0], w10, bb1)));
                    h = fmaxf(h, 0.f);
                    const float hg = h * gate[c][e];
                    mix[c][0] = fmaf(hg, w20, mix[c][0]);
                    mix[c][1] = fmaf(hg, w21, mix[c][1]);
                    mix[c][2] = fmaf(hg, w22, mix[c][2]);
                }
            }
        }
        __syncthreads();   // step-4 LDS reads retired before overwrite

        // ---- 6. mixed -> LDS as 3 aligned float4 per thread ----
        {
            float4* s4 = reinterpret_cast<float4*>(sIO);
            float m[ELEMS * OUT_DIM];
            #pragma unroll
            for (int c = 0; c < ELEMS; ++c)
                #pragma unroll
                for (int k = 0; k < OUT_DIM; ++k) m[c * OUT_DIM + k] = mix[c][k];
            #pragma unroll
            for (int k = 0; k < 3; ++k)
                s4[3 * t + k] = make_float4(m[4 * k + 0], m[4 * k + 1],
                                            m[4 * k + 2], m[4 * k + 3]);
        }
        __syncthreads();

        // ---- 7. cooperative dense mixed store: 768 float4 ----
        {
            float4* o4 = reinterpret_cast<float4*>(mixed_out + bb * OUT_DIM);
            const float4* s4 = reinterpret_cast<const float4*>(sIO);
            #pragma unroll
            for (int k = 0; k < 3; ++k) o4[t + k * BLOCK] = s4[t + k * BLOCK];
        }
    } else {
        // ---- guarded tail (never taken at B = 1M): per-element scalar ----
        for (int c = 0; c < ELEMS; ++c) {
            const long long bidx = blockBase + (long long)c * BLOCK + t;
            if (bidx >= (long long)B) continue;
            float xv[IN_DIM];
            for (int i = 0; i < IN_DIM; ++i) xv[i] = x[bidx * IN_DIM + i];

            float lg[N_EXP]; float s = 0.f;
            for (int e = 0; e < N_EXP; ++e) {
                float v = bg[e];
                for (int i = 0; i < IN_DIM; ++i)
                    v = fmaf(xv[i], Wg[i * N_EXP + e], v);
                v = __expf(v); lg[e] = v; s += v;
            }
            const float inv = 1.0f / s;
            for (int e = 0; e < N_EXP; ++e) lg[e] *= inv;

            float mixv[OUT_DIM] = {0.f, 0.f, 0.f};
            for (int e = 0; e < N_EXP; ++e) {
                for (int k = 0; k < OUT_DIM; ++k)
                    mixv[k] = fmaf(lg[e], b2[e * OUT_DIM + k], mixv[k]);
                for (int j = 0; j < HID_DIM; ++j) {
                    float h = b1[e * HID_DIM + j];
                    for (int i = 0; i < IN_DIM; ++i)
                        h = fmaf(xv[i], W1[(e * IN_DIM + i) * HID_DIM + j], h);
                    h = fmaxf(h, 0.f);
                    const float hg = h * lg[e];
                    for (int k = 0; k < OUT_DIM; ++k)
                        mixv[k] = fmaf(hg, W2[(e * HID_DIM + j) * OUT_DIM + k], mixv[k]);
                }
            }
            for (int k = 0; k < OUT_DIM; ++k)
                mixed_out[bidx * OUT_DIM + k] = mixv[k];
            for (int e = 0; e < N_EXP; ++e)
                gate_out[bidx * N_EXP + e] = lg[e];
        }
    }
}

extern "C" void kernel_launch(void* const* d_in, const int* in_sizes, int n_in,
                              void* d_out, int out_size, void* d_ws, size_t ws_size,
                              hipStream_t stream) {
    const float* x  = (const float*)d_in[0];
    const float* W1 = (const float*)d_in[1];
    const float* b1 = (const float*)d_in[2];
    const float* W2 = (const float*)d_in[3];
    const float* b2 = (const float*)d_in[4];
    const float* Wg = (const float*)d_in[5];
    const float* bg = (const float*)d_in[6];
    float* out = (float*)d_out;

    const int B = in_sizes[0] / IN_DIM;
    const int grid = (B + SPAN - 1) / SPAN;

    moe_kernel<<<grid, BLOCK, 0, stream>>>(x, W1, b1, W2, b2, Wg, bg, out, B);
}

// Round 5
// 98.657 us; speedup vs baseline: 9.8858x; 1.1043x over previous
//
#include <hip/hip_runtime.h>

#define IN_DIM  3
#define HID_DIM 20
#define OUT_DIM 3
#define N_EXP   5
#define ELEMS   4
#define PAIRS   (ELEMS / 2)
#define BLOCK   256
#define SPAN    (BLOCK * ELEMS)   // 1024 elements per block

// d_out layout: mixed [B,3] then gate [B,5], fp32.
// R4 established: dense float4 I/O through LDS + no VGPR clamp + small live
// state => no spill traffic, kernel <42us. R5: halve the VALU stream with
// packed fp32 (v_pk_fma_f32 / v_pk_max_f32) by processing element PAIRS as
// float2 ext-vectors. Expert loop: 7 pk-insts per (e,j) per pair vs 16
// scalar insts previously.

typedef float v2f __attribute__((ext_vector_type(2)));

__global__ __launch_bounds__(BLOCK) void moe_kernel(
    const float* __restrict__ x,
    const float* __restrict__ W1,   // [E, IN, HID]
    const float* __restrict__ b1,   // [E, HID]
    const float* __restrict__ W2,   // [E, HID, OUT]
    const float* __restrict__ b2,   // [E, OUT]
    const float* __restrict__ Wg,   // [IN, E]
    const float* __restrict__ bg,   // [E]
    float* __restrict__ out,
    int B)
{
    __shared__ float sIO[SPAN * N_EXP];   // 20 KB, reused: x -> gate -> mixed

    const int t = threadIdx.x;
    const long long blockBase = (long long)blockIdx.x * SPAN;
    float* __restrict__ mixed_out = out;
    float* __restrict__ gate_out  = out + (long long)B * OUT_DIM;

    if (blockBase + SPAN <= (long long)B) {
        const size_t bb = (size_t)blockBase;

        // ---- 1. cooperative dense x load: 768 float4 ----
        {
            const float4* g4 = reinterpret_cast<const float4*>(x + bb * IN_DIM);
            float4* s4 = reinterpret_cast<float4*>(sIO);
            #pragma unroll
            for (int k = 0; k < 3; ++k) s4[t + k * BLOCK] = g4[t + k * BLOCK];
        }
        __syncthreads();

        // ---- 2. per-thread x fragments (elements 4t..4t+3), packed pairs ---
        // xp[p][i] = (x[elem 2p][i], x[elem 2p+1][i])
        v2f xp[PAIRS][IN_DIM];
        {
            const float4* s4 = reinterpret_cast<const float4*>(sIO);
            float xf[ELEMS * IN_DIM];
            #pragma unroll
            for (int k = 0; k < 3; ++k) {
                float4 v = s4[3 * t + k];
                xf[4 * k + 0] = v.x; xf[4 * k + 1] = v.y;
                xf[4 * k + 2] = v.z; xf[4 * k + 3] = v.w;
            }
            #pragma unroll
            for (int p = 0; p < PAIRS; ++p)
                #pragma unroll
                for (int i = 0; i < IN_DIM; ++i)
                    xp[p][i] = (v2f){xf[(2 * p) * IN_DIM + i],
                                     (2 * p + 1) * IN_DIM + i < ELEMS * IN_DIM
                                         ? xf[(2 * p + 1) * IN_DIM + i] : 0.f};
        }
        __syncthreads();   // all x reads done before sIO is overwritten

        // ---- 3. gate: softmax(x @ Wg + bg), packed logits ----
        v2f gatep[PAIRS][N_EXP];
        #pragma unroll
        for (int p = 0; p < PAIRS; ++p) {
            v2f lg[N_EXP];
            #pragma unroll
            for (int e = 0; e < N_EXP; ++e) {
                v2f v = (v2f){bg[e], bg[e]};
                #pragma unroll
                for (int i = 0; i < IN_DIM; ++i) {
                    const float w = Wg[i * N_EXP + e];
                    v = __builtin_elementwise_fma(xp[p][i], (v2f){w, w}, v);
                }
                lg[e] = (v2f){__expf(v.x), __expf(v.y)};
            }
            v2f s = (v2f){0.f, 0.f};
            #pragma unroll
            for (int e = 0; e < N_EXP; ++e) s += lg[e];
            const v2f inv = (v2f){1.0f / s.x, 1.0f / s.y};
            #pragma unroll
            for (int e = 0; e < N_EXP; ++e) gatep[p][e] = lg[e] * inv;
        }
        // gate -> LDS as 5 aligned float4 per thread
        {
            float4* s4 = reinterpret_cast<float4*>(sIO);
            float g[ELEMS * N_EXP];
            #pragma unroll
            for (int p = 0; p < PAIRS; ++p)
                #pragma unroll
                for (int e = 0; e < N_EXP; ++e) {
                    g[(2 * p) * N_EXP + e]     = gatep[p][e].x;
                    g[(2 * p + 1) * N_EXP + e] = gatep[p][e].y;
                }
            #pragma unroll
            for (int k = 0; k < 5; ++k)
                s4[5 * t + k] = make_float4(g[4 * k + 0], g[4 * k + 1],
                                            g[4 * k + 2], g[4 * k + 3]);
        }
        __syncthreads();

        // ---- 4. cooperative dense gate store: 1280 float4 ----
        {
            float4* o4 = reinterpret_cast<float4*>(gate_out + bb * N_EXP);
            const float4* s4 = reinterpret_cast<const float4*>(sIO);
            #pragma unroll
            for (int k = 0; k < 5; ++k) o4[t + k * BLOCK] = s4[t + k * BLOCK];
        }

        // ---- 5. experts: packed pairs, 7 pk-insts per (e,j) per pair ----
        v2f mix[PAIRS][OUT_DIM];
        #pragma unroll
        for (int p = 0; p < PAIRS; ++p)
            #pragma unroll
            for (int k = 0; k < OUT_DIM; ++k) mix[p][k] = (v2f){0.f, 0.f};

        #pragma unroll
        for (int e = 0; e < N_EXP; ++e) {
            v2f oacc[PAIRS][OUT_DIM];
            #pragma unroll
            for (int p = 0; p < PAIRS; ++p)
                #pragma unroll
                for (int k = 0; k < OUT_DIM; ++k) {
                    const float bk = b2[e * OUT_DIM + k];
                    oacc[p][k] = (v2f){bk, bk};
                }
            #pragma unroll
            for (int j = 0; j < HID_DIM; ++j) {
                // 7 wave-uniform weight loads (scalar-cache) per (e,j)
                const float w10 = W1[(e * IN_DIM + 0) * HID_DIM + j];
                const float w11 = W1[(e * IN_DIM + 1) * HID_DIM + j];
                const float w12 = W1[(e * IN_DIM + 2) * HID_DIM + j];
                const float bb1 = b1[e * HID_DIM + j];
                const float w20 = W2[(e * HID_DIM + j) * OUT_DIM + 0];
                const float w21 = W2[(e * HID_DIM + j) * OUT_DIM + 1];
                const float w22 = W2[(e * HID_DIM + j) * OUT_DIM + 2];
                const v2f w10v = (v2f){w10, w10}, w11v = (v2f){w11, w11};
                const v2f w12v = (v2f){w12, w12}, bb1v = (v2f){bb1, bb1};
                const v2f w20v = (v2f){w20, w20}, w21v = (v2f){w21, w21};
                const v2f w22v = (v2f){w22, w22};
                #pragma unroll
                for (int p = 0; p < PAIRS; ++p) {
                    v2f h = __builtin_elementwise_fma(xp[p][2], w12v,
                            __builtin_elementwise_fma(xp[p][1], w11v,
                            __builtin_elementwise_fma(xp[p][0], w10v, bb1v)));
                    h = __builtin_elementwise_max(h, (v2f){0.f, 0.f});
                    oacc[p][0] = __builtin_elementwise_fma(h, w20v, oacc[p][0]);
                    oacc[p][1] = __builtin_elementwise_fma(h, w21v, oacc[p][1]);
                    oacc[p][2] = __builtin_elementwise_fma(h, w22v, oacc[p][2]);
                }
            }
            #pragma unroll
            for (int p = 0; p < PAIRS; ++p)
                #pragma unroll
                for (int k = 0; k < OUT_DIM; ++k)
                    mix[p][k] = __builtin_elementwise_fma(gatep[p][e], oacc[p][k],
                                                          mix[p][k]);
        }
        __syncthreads();   // step-4 LDS reads retired before overwrite

        // ---- 6. mixed -> LDS as 3 aligned float4 per thread ----
        {
            float4* s4 = reinterpret_cast<float4*>(sIO);
            float m[ELEMS * OUT_DIM];
            #pragma unroll
            for (int p = 0; p < PAIRS; ++p)
                #pragma unroll
                for (int k = 0; k < OUT_DIM; ++k) {
                    m[(2 * p) * OUT_DIM + k]     = mix[p][k].x;
                    m[(2 * p + 1) * OUT_DIM + k] = mix[p][k].y;
                }
            #pragma unroll
            for (int k = 0; k < 3; ++k)
                s4[3 * t + k] = make_float4(m[4 * k + 0], m[4 * k + 1],
                                            m[4 * k + 2], m[4 * k + 3]);
        }
        __syncthreads();

        // ---- 7. cooperative dense mixed store: 768 float4 ----
        {
            float4* o4 = reinterpret_cast<float4*>(mixed_out + bb * OUT_DIM);
            const float4* s4 = reinterpret_cast<const float4*>(sIO);
            #pragma unroll
            for (int k = 0; k < 3; ++k) o4[t + k * BLOCK] = s4[t + k * BLOCK];
        }
    } else {
        // ---- guarded tail (never taken at B = 1M): per-element scalar ----
        for (int c = 0; c < ELEMS; ++c) {
            const long long bidx = blockBase + (long long)c * BLOCK + t;
            if (bidx >= (long long)B) continue;
            float xv[IN_DIM];
            for (int i = 0; i < IN_DIM; ++i) xv[i] = x[bidx * IN_DIM + i];

            float lg[N_EXP]; float s = 0.f;
            for (int e = 0; e < N_EXP; ++e) {
                float v = bg[e];
                for (int i = 0; i < IN_DIM; ++i)
                    v = fmaf(xv[i], Wg[i * N_EXP + e], v);
                v = __expf(v); lg[e] = v; s += v;
            }
            const float inv = 1.0f / s;
            for (int e = 0; e < N_EXP; ++e) lg[e] *= inv;

            float mixv[OUT_DIM] = {0.f, 0.f, 0.f};
            for (int e = 0; e < N_EXP; ++e) {
                for (int k = 0; k < OUT_DIM; ++k)
                    mixv[k] = fmaf(lg[e], b2[e * OUT_DIM + k], mixv[k]);
                for (int j = 0; j < HID_DIM; ++j) {
                    float h = b1[e * HID_DIM + j];
                    for (int i = 0; i < IN_DIM; ++i)
                        h = fmaf(xv[i], W1[(e * IN_DIM + i) * HID_DIM + j], h);
                    h = fmaxf(h, 0.f);
                    const float hg = h * lg[e];
                    for (int k = 0; k < OUT_DIM; ++k)
                        mixv[k] = fmaf(hg, W2[(e * HID_DIM + j) * OUT_DIM + k], mixv[k]);
                }
            }
            for (int k = 0; k < OUT_DIM; ++k)
                mixed_out[bidx * OUT_DIM + k] = mixv[k];
            for (int e = 0; e < N_EXP; ++e)
                gate_out[bidx * N_EXP + e] = lg[e];
        }
    }
}

extern "C" void kernel_launch(void* const* d_in, const int* in_sizes, int n_in,
                              void* d_out, int out_size, void* d_ws, size_t ws_size,
                              hipStream_t stream) {
    const float* x  = (const float*)d_in[0];
    const float* W1 = (const float*)d_in[1];
    const float* b1 = (const float*)d_in[2];
    const float* W2 = (const float*)d_in[3];
    const float* b2 = (const float*)d_in[4];
    const float* Wg = (const float*)d_in[5];
    const float* bg = (const float*)d_in[6];
    float* out = (float*)d_out;

    const int B = in_sizes[0] / IN_DIM;
    const int grid = (B + SPAN - 1) / SPAN;

    moe_kernel<<<grid, BLOCK, 0, stream>>>(x, W1, b1, W2, b2, Wg, bg, out, B);
}